// Round 5
// baseline (501.164 us; speedup 1.0000x reference)
//
#include <hip/hip_runtime.h>
#include <hip/hip_bf16.h>

// Problem constants (match reference)
constexpr int cN = 50000;
constexpr int cE = 800000;
constexpr int cNUM_CLASSES = 40;
constexpr int cFEAT_DIM = 256;
constexpr int cFEAT_HID = 64;
constexpr int cDEG_HID = 32;
constexpr int cHID = 128;
constexpr int cIN_CH = cNUM_CLASSES + cFEAT_HID + cDEG_HID; // 136
constexpr int cMAX_DEG = 256;
constexpr int cSCAN_NB = (cN + 255) / 256; // 196
constexpr int cHCOPIES = 8;                 // privatized histogram copies

typedef unsigned short ushort8_t __attribute__((ext_vector_type(8)));
typedef unsigned short ushort4_t __attribute__((ext_vector_type(4)));

__device__ __forceinline__ unsigned short f2bf(float f) {
    unsigned u = __builtin_bit_cast(unsigned, f);
    u += 0x7fff + ((u >> 16) & 1); // RNE
    return (unsigned short)(u >> 16);
}
__device__ __forceinline__ float bf2f(unsigned short s) {
    unsigned u = ((unsigned)s) << 16;
    return __builtin_bit_cast(float, u);
}

// ---------------- privatized degree histograms ----------------
// copy c holds [src-counts cN | dst-counts cN]
__global__ void degree_kernel(const int* __restrict__ edge, int* __restrict__ priv) {
    int e = blockIdx.x * blockDim.x + threadIdx.x;
    int* base = priv + (size_t)(blockIdx.x & (cHCOPIES - 1)) * (2 * cN);
    if (e < cE) {
        atomicAdd(&base[edge[e]], 1);
        atomicAdd(&base[cN + edge[cE + e]], 1);
    }
}

// ---------------- merge 8 privatized copies -> [count_src | count_dst] ----------------
__global__ __launch_bounds__(256) void merge_hist_kernel(const int* __restrict__ priv,
                                                         int* __restrict__ dst) {
    constexpr int TOT4 = (2 * cN) / 4; // 25000
    int i = blockIdx.x * 256 + threadIdx.x;
    if (i >= TOT4) return;
    int4 acc = make_int4(0, 0, 0, 0);
    #pragma unroll
    for (int c = 0; c < cHCOPIES; ++c) {
        int4 v = *(const int4*)&priv[(size_t)c * 2 * cN + i * 4];
        acc.x += v.x; acc.y += v.y; acc.z += v.z; acc.w += v.w;
    }
    *(int4*)&dst[i * 4] = acc;
}

// ---------------- hierarchical scan, phase 1: per-block sums ----------------
__global__ __launch_bounds__(256) void block_sum_kernel(const int* __restrict__ cnt,
                                                        int* __restrict__ bsum) {
    __shared__ int s[256];
    int tid = threadIdx.x;
    int i = blockIdx.x * 256 + tid;
    int v = (i < cN) ? cnt[i] : 0;
    s[tid] = v;
    __syncthreads();
    #pragma unroll
    for (int off = 128; off > 0; off >>= 1) {
        if (tid < off) s[tid] += s[tid + off];
        __syncthreads();
    }
    if (tid == 0) bsum[blockIdx.x] = s[0];
}

// ---------------- phase 2: exclusive scan of block sums ----------------
__global__ __launch_bounds__(256) void scan_sums_kernel(const int* __restrict__ bsum,
                                                        int* __restrict__ boff) {
    __shared__ int s[256];
    int tid = threadIdx.x;
    int v = (tid < cSCAN_NB) ? bsum[tid] : 0;
    s[tid] = v;
    __syncthreads();
    #pragma unroll
    for (int off = 1; off < 256; off <<= 1) {
        int t = (tid >= off) ? s[tid - off] : 0;
        __syncthreads();
        s[tid] += t;
        __syncthreads();
    }
    if (tid < cSCAN_NB) boff[tid] = s[tid] - v; // exclusive
}

// ---------------- phase 3: in-block scan + writeback (rowptr, cursor, dinv) ----------------
__global__ __launch_bounds__(256) void write_rowptr_kernel(const int* __restrict__ cnt,
                                                           const int* __restrict__ boff,
                                                           int* __restrict__ rowptr,
                                                           int* __restrict__ cursor,
                                                           float* __restrict__ dinv) {
    __shared__ int s[256];
    int tid = threadIdx.x;
    int i = blockIdx.x * 256 + tid;
    int v = (i < cN) ? cnt[i] : 0;
    s[tid] = v;
    __syncthreads();
    #pragma unroll
    for (int off = 1; off < 256; off <<= 1) {
        int t = (tid >= off) ? s[tid - off] : 0;
        __syncthreads();
        s[tid] += t;
        __syncthreads();
    }
    if (i < cN) {
        int ex = boff[blockIdx.x] + s[tid] - v;
        rowptr[i] = ex;
        cursor[i] = ex;
        dinv[i] = rsqrtf((float)(v + 1));
    }
    if (i == 0) rowptr[cN] = cE;
}

// ---------------- scatter edges into CSR (by dst) ----------------
__global__ void scatter_kernel(const int* __restrict__ edge, int* __restrict__ cursor,
                               int* __restrict__ adj) {
    int e = blockIdx.x * blockDim.x + threadIdx.x;
    if (e < cE) {
        int d = edge[cE + e];
        int pos = atomicAdd(&cursor[d], 1);
        adj[pos] = edge[e];
    }
}

// ---------------- x[:, 0:40] = logits ----------------
__global__ void copy_logits_kernel(const float* __restrict__ logits, float* __restrict__ x) {
    int idx = blockIdx.x * blockDim.x + threadIdx.x;
    if (idx < cN * cNUM_CLASSES) {
        int i = idx / cNUM_CLASSES;
        int c = idx - i * cNUM_CLASSES;
        x[(size_t)i * cIN_CH + c] = logits[idx];
    }
}

// ---------------- x[:, 104:136] = deg_table[clip(deg)] ----------------
__global__ void degemb_kernel(const int* __restrict__ count_src, const int* __restrict__ count_dst,
                              const float* __restrict__ deg_table, float* __restrict__ x) {
    int idx = blockIdx.x * blockDim.x + threadIdx.x;
    if (idx < cN * cDEG_HID) {
        int i = idx / cDEG_HID;
        int j = idx - i * cDEG_HID;
        int deg = count_src[i] + count_dst[i];
        if (deg > cMAX_DEG - 1) deg = cMAX_DEG - 1;
        x[(size_t)i * cIN_CH + cNUM_CLASSES + cFEAT_HID + j] = deg_table[deg * cDEG_HID + j];
    }
}

// ---------------- tiled register-blocked GEMM (fp32 math, fp32 or bf16 output) ----------------
template <int K, int KC, int OUTC, int COLS, int BLOCK, bool BIAS, typename OutT>
__global__ __launch_bounds__(BLOCK) void tile_gemm(const float* __restrict__ in,
                                                   const float* __restrict__ W,
                                                   const float* __restrict__ bias,
                                                   OutT* __restrict__ out,
                                                   int outstride, int outoffset) {
    constexpr int ROWS = 32;
    constexpr int RT = 8;            // row-tiles (4 rows each)
    constexpr int CT = COLS / 4;     // col-tiles
    static_assert(BLOCK == RT * CT, "block/tile mismatch");
    static_assert(K % KC == 0, "K must be divisible by KC");

    __shared__ float xs[KC][ROWS + 4];   // stride 36
    __shared__ float ws[KC][COLS];

    const int tid = threadIdx.x;
    const int rt = tid % RT;
    const int ct = tid / RT;
    const int rowbase = blockIdx.x * ROWS;
    const int r0 = rt * 4;
    const int c0 = ct * 4;

    float acc[4][4];
    #pragma unroll
    for (int i = 0; i < 4; ++i)
        #pragma unroll
        for (int j = 0; j < 4; ++j) acc[i][j] = 0.f;

    for (int kbase = 0; kbase < K; kbase += KC) {
        for (int idx = tid; idx < KC * (COLS / 4); idx += BLOCK) {
            int k = idx / (COLS / 4);
            int cq = (idx % (COLS / 4)) * 4;
            float4 v = make_float4(0.f, 0.f, 0.f, 0.f);
            if (cq < OUTC) v = *(const float4*)&W[(size_t)(kbase + k) * OUTC + cq];
            *(float4*)&ws[k][cq] = v;
        }
        for (int idx = tid; idx < KC * ROWS; idx += BLOCK) {
            int r = idx / KC;
            int k = idx % KC;
            int rr = rowbase + r;
            if (rr > cN - 1) rr = cN - 1;
            xs[k][r] = in[(size_t)rr * K + kbase + k];
        }
        __syncthreads();

        #pragma unroll 4
        for (int k = 0; k < KC; ++k) {
            float4 xv = *(const float4*)&xs[k][r0];
            float4 wv = *(const float4*)&ws[k][c0];
            acc[0][0] += xv.x * wv.x; acc[0][1] += xv.x * wv.y; acc[0][2] += xv.x * wv.z; acc[0][3] += xv.x * wv.w;
            acc[1][0] += xv.y * wv.x; acc[1][1] += xv.y * wv.y; acc[1][2] += xv.y * wv.z; acc[1][3] += xv.y * wv.w;
            acc[2][0] += xv.z * wv.x; acc[2][1] += xv.z * wv.y; acc[2][2] += xv.z * wv.z; acc[2][3] += xv.z * wv.w;
            acc[3][0] += xv.w * wv.x; acc[3][1] += xv.w * wv.y; acc[3][2] += xv.w * wv.z; acc[3][3] += xv.w * wv.w;
        }
        __syncthreads();
    }

    if (c0 < OUTC) {
        float4 bv = make_float4(0.f, 0.f, 0.f, 0.f);
        if (BIAS) bv = *(const float4*)&bias[c0];
        #pragma unroll
        for (int i = 0; i < 4; ++i) {
            int r = rowbase + r0 + i;
            if (r < cN) {
                float4 v = make_float4(acc[i][0] + bv.x, acc[i][1] + bv.y,
                                       acc[i][2] + bv.z, acc[i][3] + bv.w);
                if constexpr (sizeof(OutT) == 2) {
                    ushort4_t p = { f2bf(v.x), f2bf(v.y), f2bf(v.z), f2bf(v.w) };
                    *(ushort4_t*)&out[(size_t)r * outstride + outoffset + c0] = p;
                } else {
                    *(float4*)&out[(size_t)r * outstride + outoffset + c0] = v;
                }
            }
        }
    }
}

// ---------------- GCN aggregate over bf16 t, 128 channels ----------------
template <bool RELU>
__global__ __launch_bounds__(256) void agg_bf128(const unsigned short* __restrict__ t,
                                                 const int* __restrict__ rowptr,
                                                 const int* __restrict__ adj,
                                                 const float* __restrict__ dinv,
                                                 const float* __restrict__ b,
                                                 float* __restrict__ out) {
    const int tid = threadIdx.x;
    const int lane = tid & 15;
    const int row = blockIdx.x * 16 + (tid >> 4);
    if (row >= cN) return;
    const int c = lane * 8;
    const float di = dinv[row];
    const int beg = rowptr[row], end = rowptr[row + 1];
    float acc[8];
    #pragma unroll
    for (int k = 0; k < 8; ++k) acc[k] = 0.f;
    for (int e = beg; e < end; ++e) {
        int j = adj[e];
        float vj = dinv[j];
        ushort8_t tv = *(const ushort8_t*)&t[(size_t)j * cHID + c];
        #pragma unroll
        for (int k = 0; k < 8; ++k) acc[k] += vj * bf2f(tv[k]);
    }
    ushort8_t ts = *(const ushort8_t*)&t[(size_t)row * cHID + c];
    const float d2 = di * di;
    float r[8];
    #pragma unroll
    for (int k = 0; k < 8; ++k) {
        r[k] = di * acc[k] + d2 * bf2f(ts[k]) + b[c + k];
        if (RELU) r[k] = fmaxf(r[k], 0.f);
    }
    float4 v0 = make_float4(r[0], r[1], r[2], r[3]);
    float4 v1 = make_float4(r[4], r[5], r[6], r[7]);
    *(float4*)&out[(size_t)row * cHID + c] = v0;
    *(float4*)&out[(size_t)row * cHID + c + 4] = v1;
}

// ---------------- GCN aggregate over bf16 t, 40 channels (final, no relu) ----------------
__global__ __launch_bounds__(256) void agg_bf40(const unsigned short* __restrict__ t,
                                                const int* __restrict__ rowptr,
                                                const int* __restrict__ adj,
                                                const float* __restrict__ dinv,
                                                const float* __restrict__ b,
                                                float* __restrict__ out) {
    const int tid = threadIdx.x;
    const int lane = tid & 7;
    const int row = blockIdx.x * 32 + (tid >> 3);
    if (row >= cN) return;
    const int c = lane * 8;
    if (c >= cNUM_CLASSES) return;   // lanes 5-7 idle
    const float di = dinv[row];
    const int beg = rowptr[row], end = rowptr[row + 1];
    float acc[8];
    #pragma unroll
    for (int k = 0; k < 8; ++k) acc[k] = 0.f;
    for (int e = beg; e < end; ++e) {
        int j = adj[e];
        float vj = dinv[j];
        ushort8_t tv = *(const ushort8_t*)&t[(size_t)j * cNUM_CLASSES + c];
        #pragma unroll
        for (int k = 0; k < 8; ++k) acc[k] += vj * bf2f(tv[k]);
    }
    ushort8_t ts = *(const ushort8_t*)&t[(size_t)row * cNUM_CLASSES + c];
    const float d2 = di * di;
    float r[8];
    #pragma unroll
    for (int k = 0; k < 8; ++k) r[k] = di * acc[k] + d2 * bf2f(ts[k]) + b[c + k];
    float4 v0 = make_float4(r[0], r[1], r[2], r[3]);
    float4 v1 = make_float4(r[4], r[5], r[6], r[7]);
    *(float4*)&out[(size_t)row * cNUM_CLASSES + c] = v0;
    *(float4*)&out[(size_t)row * cNUM_CLASSES + c + 4] = v1;
}

extern "C" void kernel_launch(void* const* d_in, const int* in_sizes, int n_in,
                              void* d_out, int out_size, void* d_ws, size_t ws_size,
                              hipStream_t stream) {
    const float* logits    = (const float*)d_in[0];
    const float* features  = (const float*)d_in[1];
    const int*   edge      = (const int*)d_in[2];
    const float* Wf        = (const float*)d_in[3];
    const float* bf        = (const float*)d_in[4];
    const float* deg_table = (const float*)d_in[5];
    const float* W1        = (const float*)d_in[6];
    const float* b1        = (const float*)d_in[7];
    const float* W2        = (const float*)d_in[8];
    const float* b2        = (const float*)d_in[9];
    const float* W3        = (const float*)d_in[10];
    const float* b3        = (const float*)d_in[11];
    float* out = (float*)d_out;

    // workspace carve-up (all offsets keep 16B alignment)
    int* count_src = (int*)d_ws;                 // N   (merged, contiguous with count_dst)
    int* count_dst = count_src + cN;             // N
    int* rowptr    = count_dst + cN;             // N+1 (pad to +16)
    int* cursor    = rowptr + cN + 16;           // N
    int* adj       = cursor + cN;                // E
    int* bsum      = adj + cE;                   // 256
    int* boff      = bsum + 256;                 // 256
    float* dinv    = (float*)(boff + 256);       // N
    float* x       = dinv + cN;                  // N*IN_CH
    float* h       = x + (size_t)cN * cIN_CH;    // N*HID fp32
    unsigned short* tb = (unsigned short*)(h + (size_t)cN * cHID); // N*HID bf16
    int* priv      = (int*)(tb + (size_t)cN * cHID); // HCOPIES * 2N ints

    hipMemsetAsync(priv, 0, (size_t)cHCOPIES * 2 * cN * sizeof(int), stream);

    degree_kernel<<<(cE + 255) / 256, 256, 0, stream>>>(edge, priv);
    merge_hist_kernel<<<(2 * cN / 4 + 255) / 256, 256, 0, stream>>>(priv, count_src);
    block_sum_kernel<<<cSCAN_NB, 256, 0, stream>>>(count_dst, bsum);
    scan_sums_kernel<<<1, 256, 0, stream>>>(bsum, boff);
    write_rowptr_kernel<<<cSCAN_NB, 256, 0, stream>>>(count_dst, boff, rowptr, cursor, dinv);
    scatter_kernel<<<(cE + 255) / 256, 256, 0, stream>>>(edge, cursor, adj);

    copy_logits_kernel<<<(cN * cNUM_CLASSES + 255) / 256, 256, 0, stream>>>(logits, x);
    degemb_kernel<<<(cN * cDEG_HID + 255) / 256, 256, 0, stream>>>(count_src, count_dst, deg_table, x);

    constexpr int NBLK = (cN + 31) / 32; // 1563

    // featlin: x[:,40:104] = features @ Wf + bf
    tile_gemm<cFEAT_DIM, 64, cFEAT_HID, 64, 128, true, float>
        <<<NBLK, 128, 0, stream>>>(features, Wf, bf, x, cIN_CH, cNUM_CLASSES);

    // conv1: tb = bf16(x @ W1) ; h = relu(agg(tb) + b1)
    tile_gemm<cIN_CH, 68, cHID, 128, 256, false, unsigned short>
        <<<NBLK, 256, 0, stream>>>(x, W1, nullptr, tb, cHID, 0);
    agg_bf128<true><<<(cN + 15) / 16, 256, 0, stream>>>(tb, rowptr, adj, dinv, b1, h);

    // conv2: tb = bf16(h @ W2) ; h = relu(agg(tb) + b2)
    tile_gemm<cHID, 64, cHID, 128, 256, false, unsigned short>
        <<<NBLK, 256, 0, stream>>>(h, W2, nullptr, tb, cHID, 0);
    agg_bf128<true><<<(cN + 15) / 16, 256, 0, stream>>>(tb, rowptr, adj, dinv, b2, h);

    // conv3: tb = bf16(h @ W3) ; out = agg(tb) + b3
    tile_gemm<cHID, 64, cNUM_CLASSES, 64, 128, false, unsigned short>
        <<<NBLK, 128, 0, stream>>>(h, W3, nullptr, tb, cNUM_CLASSES, 0);
    agg_bf40<<<(cN + 31) / 32, 256, 0, stream>>>(tb, rowptr, adj, dinv, b3, out);
}

// Round 6
// 445.713 us; speedup vs baseline: 1.1244x; 1.1244x over previous
//
#include <hip/hip_runtime.h>
#include <hip/hip_bf16.h>

// Problem constants (match reference)
constexpr int cN = 50000;
constexpr int cE = 800000;
constexpr int cNUM_CLASSES = 40;
constexpr int cFEAT_DIM = 256;
constexpr int cFEAT_HID = 64;
constexpr int cDEG_HID = 32;
constexpr int cHID = 128;
constexpr int cIN_CH = cNUM_CLASSES + cFEAT_HID + cDEG_HID; // 136
constexpr int cMAX_DEG = 256;
constexpr int cSCAN_NB = (cN + 255) / 256; // 196

// LDS-histogram CSR build parameters
constexpr int cNCHUNK = 128;            // edge chunks (= copies per histogram)
constexpr int cCHUNK  = cE / cNCHUNK;   // 6250 edges per chunk (exact)
constexpr int cWORDS  = cN / 2;         // 25000 packed u16-pair words per histogram
constexpr int cHWORDS = cWORDS / 2;     // 12500 words per node-range half (50 KB LDS)

typedef unsigned short ushort8_t __attribute__((ext_vector_type(8)));
typedef unsigned short ushort4_t __attribute__((ext_vector_type(4)));

__device__ __forceinline__ unsigned short f2bf(float f) {
    unsigned u = __builtin_bit_cast(unsigned, f);
    u += 0x7fff + ((u >> 16) & 1); // RNE
    return (unsigned short)(u >> 16);
}
__device__ __forceinline__ float bf2f(unsigned short s) {
    unsigned u = ((unsigned)s) << 16;
    return __builtin_bit_cast(float, u);
}

// ---------------- LDS histogram: partial[which][chunk][word] (packed u16 pair) ----------------
// grid = 512: cb = b&127 (chunk), half = (b>>7)&1 (node range), which = b>>8 (0:src 1:dst)
__global__ __launch_bounds__(256) void hist_kernel(const int* __restrict__ edge,
                                                   unsigned* __restrict__ partial) {
    __shared__ unsigned lds[cHWORDS];
    const int b = blockIdx.x, tid = threadIdx.x;
    const int cb = b & (cNCHUNK - 1);
    const int half = (b >> 7) & 1;
    const int which = b >> 8;
    for (int i = tid; i < cHWORDS; i += 256) lds[i] = 0;
    __syncthreads();
    const int* ids = edge + (size_t)which * cE + (size_t)cb * cCHUNK;
    const int lo = half * (cN / 2), hi = lo + cN / 2;
    const int wbase = half * cHWORDS;
    for (int i = tid; i < cCHUNK; i += 256) {
        int v = ids[i];
        if (v >= lo && v < hi)
            atomicAdd(&lds[(v >> 1) - wbase], 1u << ((v & 1) * 16));
    }
    __syncthreads();
    unsigned* outp = partial + ((size_t)which * cNCHUNK + cb) * cWORDS + wbase;
    for (int i = tid; i < cHWORDS; i += 256) outp[i] = lds[i];
}

// ---------------- merge copies -> counts; rewrite dst-partial with cross-chunk prefix ----------------
__global__ __launch_bounds__(256) void merge_scan_kernel(unsigned* __restrict__ partial,
                                                         int* __restrict__ count_src,
                                                         int* __restrict__ count_dst) {
    const int w = blockIdx.x * 256 + threadIdx.x;
    if (w >= cWORDS) return;
    // src histogram: plain sum
    unsigned slo = 0, shi = 0;
    const unsigned* ps = partial + w;
    for (int c = 0; c < cNCHUNK; ++c) {
        unsigned v = ps[(size_t)c * cWORDS];
        slo += v & 0xFFFFu; shi += v >> 16;
    }
    *(int2*)&count_src[2 * w] = make_int2((int)slo, (int)shi);
    // dst histogram: running prefix across chunks (rewrite in place), then total
    unsigned plo = 0, phi = 0;
    unsigned* pd = partial + (size_t)cNCHUNK * cWORDS + w;
    for (int c = 0; c < cNCHUNK; ++c) {
        unsigned v = pd[(size_t)c * cWORDS];
        pd[(size_t)c * cWORDS] = plo | (phi << 16);   // prefix fits u16 (<= max degree)
        plo += v & 0xFFFFu; phi += v >> 16;
    }
    *(int2*)&count_dst[2 * w] = make_int2((int)plo, (int)phi);
}

// ---------------- hierarchical scan, phase 1: per-block sums ----------------
__global__ __launch_bounds__(256) void block_sum_kernel(const int* __restrict__ cnt,
                                                        int* __restrict__ bsum) {
    __shared__ int s[256];
    int tid = threadIdx.x;
    int i = blockIdx.x * 256 + tid;
    int v = (i < cN) ? cnt[i] : 0;
    s[tid] = v;
    __syncthreads();
    #pragma unroll
    for (int off = 128; off > 0; off >>= 1) {
        if (tid < off) s[tid] += s[tid + off];
        __syncthreads();
    }
    if (tid == 0) bsum[blockIdx.x] = s[0];
}

// ---------------- phase 2: exclusive scan of block sums ----------------
__global__ __launch_bounds__(256) void scan_sums_kernel(const int* __restrict__ bsum,
                                                        int* __restrict__ boff) {
    __shared__ int s[256];
    int tid = threadIdx.x;
    int v = (tid < cSCAN_NB) ? bsum[tid] : 0;
    s[tid] = v;
    __syncthreads();
    #pragma unroll
    for (int off = 1; off < 256; off <<= 1) {
        int t = (tid >= off) ? s[tid - off] : 0;
        __syncthreads();
        s[tid] += t;
        __syncthreads();
    }
    if (tid < cSCAN_NB) boff[tid] = s[tid] - v; // exclusive
}

// ---------------- phase 3: in-block scan + writeback (rowptr, dinv) ----------------
__global__ __launch_bounds__(256) void write_rowptr_kernel(const int* __restrict__ cnt,
                                                           const int* __restrict__ boff,
                                                           int* __restrict__ rowptr,
                                                           float* __restrict__ dinv) {
    __shared__ int s[256];
    int tid = threadIdx.x;
    int i = blockIdx.x * 256 + tid;
    int v = (i < cN) ? cnt[i] : 0;
    s[tid] = v;
    __syncthreads();
    #pragma unroll
    for (int off = 1; off < 256; off <<= 1) {
        int t = (tid >= off) ? s[tid - off] : 0;
        __syncthreads();
        s[tid] += t;
        __syncthreads();
    }
    if (i < cN) {
        rowptr[i] = boff[blockIdx.x] + s[tid] - v;
        dinv[i] = rsqrtf((float)(v + 1));
    }
    if (i == 0) rowptr[cN] = cE;
}

// ---------------- deterministic scatter using per-chunk prefixes (no global atomics) ----------------
// grid = 256: cb = b&127 (chunk), half = b>>7 (node range)
__global__ __launch_bounds__(256) void scatter2_kernel(const int* __restrict__ edge,
                                                       const unsigned* __restrict__ partial,
                                                       const int* __restrict__ rowptr,
                                                       int* __restrict__ adj) {
    __shared__ unsigned lds[cHWORDS];
    const int b = blockIdx.x, tid = threadIdx.x;
    const int cb = b & (cNCHUNK - 1);
    const int half = b >> 7;
    const int wbase = half * cHWORDS;
    const unsigned* pp = partial + ((size_t)cNCHUNK + cb) * cWORDS + wbase; // dst slab
    for (int i = tid; i < cHWORDS; i += 256) lds[i] = pp[i];
    __syncthreads();
    const int* srcs = edge + (size_t)cb * cCHUNK;
    const int* dsts = edge + cE + (size_t)cb * cCHUNK;
    const int lo = half * (cN / 2), hi = lo + cN / 2;
    for (int i = tid; i < cCHUNK; i += 256) {
        int d = dsts[i];
        if (d >= lo && d < hi) {
            int sh = (d & 1) * 16;
            unsigned old = atomicAdd(&lds[(d >> 1) - wbase], 1u << sh);
            int off = (int)((old >> sh) & 0xFFFFu);
            adj[rowptr[d] + off] = srcs[i];
        }
    }
}

// ---------------- x[:, 0:40] = logits ----------------
__global__ void copy_logits_kernel(const float* __restrict__ logits, float* __restrict__ x) {
    int idx = blockIdx.x * blockDim.x + threadIdx.x;
    if (idx < cN * cNUM_CLASSES) {
        int i = idx / cNUM_CLASSES;
        int c = idx - i * cNUM_CLASSES;
        x[(size_t)i * cIN_CH + c] = logits[idx];
    }
}

// ---------------- x[:, 104:136] = deg_table[clip(deg)] ----------------
__global__ void degemb_kernel(const int* __restrict__ count_src, const int* __restrict__ count_dst,
                              const float* __restrict__ deg_table, float* __restrict__ x) {
    int idx = blockIdx.x * blockDim.x + threadIdx.x;
    if (idx < cN * cDEG_HID) {
        int i = idx / cDEG_HID;
        int j = idx - i * cDEG_HID;
        int deg = count_src[i] + count_dst[i];
        if (deg > cMAX_DEG - 1) deg = cMAX_DEG - 1;
        x[(size_t)i * cIN_CH + cNUM_CLASSES + cFEAT_HID + j] = deg_table[deg * cDEG_HID + j];
    }
}

// ---------------- tiled register-blocked GEMM (fp32 math, fp32 or bf16 output) ----------------
template <int K, int KC, int OUTC, int COLS, int BLOCK, bool BIAS, typename OutT>
__global__ __launch_bounds__(BLOCK) void tile_gemm(const float* __restrict__ in,
                                                   const float* __restrict__ W,
                                                   const float* __restrict__ bias,
                                                   OutT* __restrict__ out,
                                                   int outstride, int outoffset) {
    constexpr int ROWS = 32;
    constexpr int RT = 8;            // row-tiles (4 rows each)
    constexpr int CT = COLS / 4;     // col-tiles
    static_assert(BLOCK == RT * CT, "block/tile mismatch");
    static_assert(K % KC == 0, "K must be divisible by KC");

    __shared__ float xs[KC][ROWS + 4];   // stride 36
    __shared__ float ws[KC][COLS];

    const int tid = threadIdx.x;
    const int rt = tid % RT;
    const int ct = tid / RT;
    const int rowbase = blockIdx.x * ROWS;
    const int r0 = rt * 4;
    const int c0 = ct * 4;

    float acc[4][4];
    #pragma unroll
    for (int i = 0; i < 4; ++i)
        #pragma unroll
        for (int j = 0; j < 4; ++j) acc[i][j] = 0.f;

    for (int kbase = 0; kbase < K; kbase += KC) {
        for (int idx = tid; idx < KC * (COLS / 4); idx += BLOCK) {
            int k = idx / (COLS / 4);
            int cq = (idx % (COLS / 4)) * 4;
            float4 v = make_float4(0.f, 0.f, 0.f, 0.f);
            if (cq < OUTC) v = *(const float4*)&W[(size_t)(kbase + k) * OUTC + cq];
            *(float4*)&ws[k][cq] = v;
        }
        for (int idx = tid; idx < KC * ROWS; idx += BLOCK) {
            int r = idx / KC;
            int k = idx % KC;
            int rr = rowbase + r;
            if (rr > cN - 1) rr = cN - 1;
            xs[k][r] = in[(size_t)rr * K + kbase + k];
        }
        __syncthreads();

        #pragma unroll 4
        for (int k = 0; k < KC; ++k) {
            float4 xv = *(const float4*)&xs[k][r0];
            float4 wv = *(const float4*)&ws[k][c0];
            acc[0][0] += xv.x * wv.x; acc[0][1] += xv.x * wv.y; acc[0][2] += xv.x * wv.z; acc[0][3] += xv.x * wv.w;
            acc[1][0] += xv.y * wv.x; acc[1][1] += xv.y * wv.y; acc[1][2] += xv.y * wv.z; acc[1][3] += xv.y * wv.w;
            acc[2][0] += xv.z * wv.x; acc[2][1] += xv.z * wv.y; acc[2][2] += xv.z * wv.z; acc[2][3] += xv.z * wv.w;
            acc[3][0] += xv.w * wv.x; acc[3][1] += xv.w * wv.y; acc[3][2] += xv.w * wv.z; acc[3][3] += xv.w * wv.w;
        }
        __syncthreads();
    }

    if (c0 < OUTC) {
        float4 bv = make_float4(0.f, 0.f, 0.f, 0.f);
        if (BIAS) bv = *(const float4*)&bias[c0];
        #pragma unroll
        for (int i = 0; i < 4; ++i) {
            int r = rowbase + r0 + i;
            if (r < cN) {
                float4 v = make_float4(acc[i][0] + bv.x, acc[i][1] + bv.y,
                                       acc[i][2] + bv.z, acc[i][3] + bv.w);
                if constexpr (sizeof(OutT) == 2) {
                    ushort4_t p = { f2bf(v.x), f2bf(v.y), f2bf(v.z), f2bf(v.w) };
                    *(ushort4_t*)&out[(size_t)r * outstride + outoffset + c0] = p;
                } else {
                    *(float4*)&out[(size_t)r * outstride + outoffset + c0] = v;
                }
            }
        }
    }
}

// ---------------- GCN aggregate over bf16 t, 128 channels ----------------
template <bool RELU>
__global__ __launch_bounds__(256) void agg_bf128(const unsigned short* __restrict__ t,
                                                 const int* __restrict__ rowptr,
                                                 const int* __restrict__ adj,
                                                 const float* __restrict__ dinv,
                                                 const float* __restrict__ b,
                                                 float* __restrict__ out) {
    const int tid = threadIdx.x;
    const int lane = tid & 15;
    const int row = blockIdx.x * 16 + (tid >> 4);
    if (row >= cN) return;
    const int c = lane * 8;
    const float di = dinv[row];
    const int beg = rowptr[row], end = rowptr[row + 1];
    float acc[8];
    #pragma unroll
    for (int k = 0; k < 8; ++k) acc[k] = 0.f;
    for (int e = beg; e < end; ++e) {
        int j = adj[e];
        float vj = dinv[j];
        ushort8_t tv = *(const ushort8_t*)&t[(size_t)j * cHID + c];
        #pragma unroll
        for (int k = 0; k < 8; ++k) acc[k] += vj * bf2f(tv[k]);
    }
    ushort8_t ts = *(const ushort8_t*)&t[(size_t)row * cHID + c];
    const float d2 = di * di;
    float r[8];
    #pragma unroll
    for (int k = 0; k < 8; ++k) {
        r[k] = di * acc[k] + d2 * bf2f(ts[k]) + b[c + k];
        if (RELU) r[k] = fmaxf(r[k], 0.f);
    }
    float4 v0 = make_float4(r[0], r[1], r[2], r[3]);
    float4 v1 = make_float4(r[4], r[5], r[6], r[7]);
    *(float4*)&out[(size_t)row * cHID + c] = v0;
    *(float4*)&out[(size_t)row * cHID + c + 4] = v1;
}

// ---------------- GCN aggregate over bf16 t, 40 channels (final, no relu) ----------------
__global__ __launch_bounds__(256) void agg_bf40(const unsigned short* __restrict__ t,
                                                const int* __restrict__ rowptr,
                                                const int* __restrict__ adj,
                                                const float* __restrict__ dinv,
                                                const float* __restrict__ b,
                                                float* __restrict__ out) {
    const int tid = threadIdx.x;
    const int lane = tid & 7;
    const int row = blockIdx.x * 32 + (tid >> 3);
    if (row >= cN) return;
    const int c = lane * 8;
    if (c >= cNUM_CLASSES) return;   // lanes 5-7 idle
    const float di = dinv[row];
    const int beg = rowptr[row], end = rowptr[row + 1];
    float acc[8];
    #pragma unroll
    for (int k = 0; k < 8; ++k) acc[k] = 0.f;
    for (int e = beg; e < end; ++e) {
        int j = adj[e];
        float vj = dinv[j];
        ushort8_t tv = *(const ushort8_t*)&t[(size_t)j * cNUM_CLASSES + c];
        #pragma unroll
        for (int k = 0; k < 8; ++k) acc[k] += vj * bf2f(tv[k]);
    }
    ushort8_t ts = *(const ushort8_t*)&t[(size_t)row * cNUM_CLASSES + c];
    const float d2 = di * di;
    float r[8];
    #pragma unroll
    for (int k = 0; k < 8; ++k) r[k] = di * acc[k] + d2 * bf2f(ts[k]) + b[c + k];
    float4 v0 = make_float4(r[0], r[1], r[2], r[3]);
    float4 v1 = make_float4(r[4], r[5], r[6], r[7]);
    *(float4*)&out[(size_t)row * cNUM_CLASSES + c] = v0;
    *(float4*)&out[(size_t)row * cNUM_CLASSES + c + 4] = v1;
}

extern "C" void kernel_launch(void* const* d_in, const int* in_sizes, int n_in,
                              void* d_out, int out_size, void* d_ws, size_t ws_size,
                              hipStream_t stream) {
    const float* logits    = (const float*)d_in[0];
    const float* features  = (const float*)d_in[1];
    const int*   edge      = (const int*)d_in[2];
    const float* Wf        = (const float*)d_in[3];
    const float* bf        = (const float*)d_in[4];
    const float* deg_table = (const float*)d_in[5];
    const float* W1        = (const float*)d_in[6];
    const float* b1        = (const float*)d_in[7];
    const float* W2        = (const float*)d_in[8];
    const float* b2        = (const float*)d_in[9];
    const float* W3        = (const float*)d_in[10];
    const float* b3        = (const float*)d_in[11];
    float* out = (float*)d_out;

    // workspace carve-up (16B-aligned sections)
    int* count_src = (int*)d_ws;                 // N
    int* count_dst = count_src + cN;             // N
    int* rowptr    = count_dst + cN;             // N+1 (padded)
    int* adj       = rowptr + cN + 16;           // E
    int* bsum      = adj + cE;                   // 256
    int* boff      = bsum + 256;                 // 256
    float* dinv    = (float*)(boff + 256);       // N
    float* x       = dinv + cN;                  // N*IN_CH fp32
    float* h       = x + (size_t)cN * cIN_CH;    // N*HID fp32
    unsigned short* tb = (unsigned short*)(h + (size_t)cN * cHID); // N*HID bf16
    unsigned* partial = (unsigned*)(tb + (size_t)cN * cHID);       // 2*128*25000 u32

    // CSR + degrees, no global atomics
    hist_kernel<<<512, 256, 0, stream>>>(edge, partial);
    merge_scan_kernel<<<(cWORDS + 255) / 256, 256, 0, stream>>>(partial, count_src, count_dst);
    block_sum_kernel<<<cSCAN_NB, 256, 0, stream>>>(count_dst, bsum);
    scan_sums_kernel<<<1, 256, 0, stream>>>(bsum, boff);
    write_rowptr_kernel<<<cSCAN_NB, 256, 0, stream>>>(count_dst, boff, rowptr, dinv);
    scatter2_kernel<<<256, 256, 0, stream>>>(edge, partial, rowptr, adj);

    copy_logits_kernel<<<(cN * cNUM_CLASSES + 255) / 256, 256, 0, stream>>>(logits, x);
    degemb_kernel<<<(cN * cDEG_HID + 255) / 256, 256, 0, stream>>>(count_src, count_dst, deg_table, x);

    constexpr int NBLK = (cN + 31) / 32; // 1563

    // featlin: x[:,40:104] = features @ Wf + bf
    tile_gemm<cFEAT_DIM, 64, cFEAT_HID, 64, 128, true, float>
        <<<NBLK, 128, 0, stream>>>(features, Wf, bf, x, cIN_CH, cNUM_CLASSES);

    // conv1: tb = bf16(x @ W1) ; h = relu(agg(tb) + b1)
    tile_gemm<cIN_CH, 68, cHID, 128, 256, false, unsigned short>
        <<<NBLK, 256, 0, stream>>>(x, W1, nullptr, tb, cHID, 0);
    agg_bf128<true><<<(cN + 15) / 16, 256, 0, stream>>>(tb, rowptr, adj, dinv, b1, h);

    // conv2: tb = bf16(h @ W2) ; h = relu(agg(tb) + b2)
    tile_gemm<cHID, 64, cHID, 128, 256, false, unsigned short>
        <<<NBLK, 256, 0, stream>>>(h, W2, nullptr, tb, cHID, 0);
    agg_bf128<true><<<(cN + 15) / 16, 256, 0, stream>>>(tb, rowptr, adj, dinv, b2, h);

    // conv3: tb = bf16(h @ W3) ; out = agg(tb) + b3
    tile_gemm<cHID, 64, cNUM_CLASSES, 64, 128, false, unsigned short>
        <<<NBLK, 128, 0, stream>>>(h, W3, nullptr, tb, cNUM_CLASSES, 0);
    agg_bf40<<<(cN + 31) / 32, 256, 0, stream>>>(tb, rowptr, adj, dinv, b3, out);
}

// Round 7
// 342.529 us; speedup vs baseline: 1.4631x; 1.3012x over previous
//
#include <hip/hip_runtime.h>
#include <hip/hip_bf16.h>

// Problem constants (match reference)
constexpr int cN = 50000;
constexpr int cE = 800000;
constexpr int cNUM_CLASSES = 40;
constexpr int cFEAT_DIM = 256;
constexpr int cFEAT_HID = 64;
constexpr int cDEG_HID = 32;
constexpr int cHID = 128;
constexpr int cIN_CH = cNUM_CLASSES + cFEAT_HID + cDEG_HID; // 136
constexpr int cKPAD = 160;              // IN_CH padded to multiple of 32
constexpr int cMAX_DEG = 256;
constexpr int cSCAN_NB = (cN + 255) / 256; // 196

// LDS-histogram CSR build parameters
constexpr int cNCHUNK = 128;            // edge chunks (= copies per histogram)
constexpr int cCHUNK  = cE / cNCHUNK;   // 6250 edges per chunk (exact)
constexpr int cWORDS  = cN / 2;         // 25000 packed u16-pair words per histogram
constexpr int cHWORDS = cWORDS / 2;     // 12500 words per node-range half (50 KB LDS)

typedef unsigned short ushort8_t __attribute__((ext_vector_type(8)));
typedef short short8_t __attribute__((ext_vector_type(8)));
typedef float float4_t __attribute__((ext_vector_type(4)));

__device__ __forceinline__ unsigned short f2bf(float f) {
    unsigned u = __builtin_bit_cast(unsigned, f);
    u += 0x7fff + ((u >> 16) & 1); // RNE
    return (unsigned short)(u >> 16);
}
__device__ __forceinline__ float bf2f(unsigned short s) {
    unsigned u = ((unsigned)s) << 16;
    return __builtin_bit_cast(float, u);
}

// ---------------- LDS histogram: partial[which][chunk][word] (packed u16 pair) ----------------
__global__ __launch_bounds__(256) void hist_kernel(const int* __restrict__ edge,
                                                   unsigned* __restrict__ partial) {
    __shared__ unsigned lds[cHWORDS];
    const int b = blockIdx.x, tid = threadIdx.x;
    const int cb = b & (cNCHUNK - 1);
    const int half = (b >> 7) & 1;
    const int which = b >> 8;
    for (int i = tid; i < cHWORDS; i += 256) lds[i] = 0;
    __syncthreads();
    const int* ids = edge + (size_t)which * cE + (size_t)cb * cCHUNK;
    const int lo = half * (cN / 2), hi = lo + cN / 2;
    const int wbase = half * cHWORDS;
    for (int i = tid; i < cCHUNK; i += 256) {
        int v = ids[i];
        if (v >= lo && v < hi)
            atomicAdd(&lds[(v >> 1) - wbase], 1u << ((v & 1) * 16));
    }
    __syncthreads();
    unsigned* outp = partial + ((size_t)which * cNCHUNK + cb) * cWORDS + wbase;
    for (int i = tid; i < cHWORDS; i += 256) outp[i] = lds[i];
}

// ---------------- merge copies -> counts; rewrite dst-partial with cross-chunk prefix ----------------
__global__ __launch_bounds__(256) void merge_scan_kernel(unsigned* __restrict__ partial,
                                                         int* __restrict__ count_src,
                                                         int* __restrict__ count_dst) {
    const int w = blockIdx.x * 256 + threadIdx.x;
    if (w >= cWORDS) return;
    unsigned slo = 0, shi = 0;
    const unsigned* ps = partial + w;
    for (int c = 0; c < cNCHUNK; ++c) {
        unsigned v = ps[(size_t)c * cWORDS];
        slo += v & 0xFFFFu; shi += v >> 16;
    }
    *(int2*)&count_src[2 * w] = make_int2((int)slo, (int)shi);
    unsigned plo = 0, phi = 0;
    unsigned* pd = partial + (size_t)cNCHUNK * cWORDS + w;
    for (int c = 0; c < cNCHUNK; ++c) {
        unsigned v = pd[(size_t)c * cWORDS];
        pd[(size_t)c * cWORDS] = plo | (phi << 16);
        plo += v & 0xFFFFu; phi += v >> 16;
    }
    *(int2*)&count_dst[2 * w] = make_int2((int)plo, (int)phi);
}

// ---------------- hierarchical scan ----------------
__global__ __launch_bounds__(256) void block_sum_kernel(const int* __restrict__ cnt,
                                                        int* __restrict__ bsum) {
    __shared__ int s[256];
    int tid = threadIdx.x;
    int i = blockIdx.x * 256 + tid;
    int v = (i < cN) ? cnt[i] : 0;
    s[tid] = v;
    __syncthreads();
    #pragma unroll
    for (int off = 128; off > 0; off >>= 1) {
        if (tid < off) s[tid] += s[tid + off];
        __syncthreads();
    }
    if (tid == 0) bsum[blockIdx.x] = s[0];
}

__global__ __launch_bounds__(256) void scan_sums_kernel(const int* __restrict__ bsum,
                                                        int* __restrict__ boff) {
    __shared__ int s[256];
    int tid = threadIdx.x;
    int v = (tid < cSCAN_NB) ? bsum[tid] : 0;
    s[tid] = v;
    __syncthreads();
    #pragma unroll
    for (int off = 1; off < 256; off <<= 1) {
        int t = (tid >= off) ? s[tid - off] : 0;
        __syncthreads();
        s[tid] += t;
        __syncthreads();
    }
    if (tid < cSCAN_NB) boff[tid] = s[tid] - v;
}

__global__ __launch_bounds__(256) void write_rowptr_kernel(const int* __restrict__ cnt,
                                                           const int* __restrict__ boff,
                                                           int* __restrict__ rowptr,
                                                           float* __restrict__ dinv) {
    __shared__ int s[256];
    int tid = threadIdx.x;
    int i = blockIdx.x * 256 + tid;
    int v = (i < cN) ? cnt[i] : 0;
    s[tid] = v;
    __syncthreads();
    #pragma unroll
    for (int off = 1; off < 256; off <<= 1) {
        int t = (tid >= off) ? s[tid - off] : 0;
        __syncthreads();
        s[tid] += t;
        __syncthreads();
    }
    if (i < cN) {
        rowptr[i] = boff[blockIdx.x] + s[tid] - v;
        dinv[i] = rsqrtf((float)(v + 1));
    }
    if (i == 0) rowptr[cN] = cE;
}

// ---------------- deterministic scatter (no global atomics) ----------------
__global__ __launch_bounds__(256) void scatter2_kernel(const int* __restrict__ edge,
                                                       const unsigned* __restrict__ partial,
                                                       const int* __restrict__ rowptr,
                                                       int* __restrict__ adj) {
    __shared__ unsigned lds[cHWORDS];
    const int b = blockIdx.x, tid = threadIdx.x;
    const int cb = b & (cNCHUNK - 1);
    const int half = b >> 7;
    const int wbase = half * cHWORDS;
    const unsigned* pp = partial + ((size_t)cNCHUNK + cb) * cWORDS + wbase;
    for (int i = tid; i < cHWORDS; i += 256) lds[i] = pp[i];
    __syncthreads();
    const int* srcs = edge + (size_t)cb * cCHUNK;
    const int* dsts = edge + cE + (size_t)cb * cCHUNK;
    const int lo = half * (cN / 2), hi = lo + cN / 2;
    for (int i = tid; i < cCHUNK; i += 256) {
        int d = dsts[i];
        if (d >= lo && d < hi) {
            int sh = (d & 1) * 16;
            unsigned old = atomicAdd(&lds[(d >> 1) - wbase], 1u << sh);
            int off = (int)((old >> sh) & 0xFFFFu);
            adj[rowptr[d] + off] = srcs[i];
        }
    }
}

// ---------------- weight convert+transpose: W[k][n] fp32 -> Wt[n][k] bf16 (with padding) ----------------
// regions: Wtf [64][256] | Wt1 [128][160] (k>=136 zero) | Wt2 [128][128] | Wt3 [48][128] (n>=40 zero)
__global__ __launch_bounds__(256) void wconv_kernel(const float* __restrict__ Wf,
                                                    const float* __restrict__ W1,
                                                    const float* __restrict__ W2,
                                                    const float* __restrict__ W3,
                                                    unsigned short* __restrict__ Wtf,
                                                    unsigned short* __restrict__ Wt1,
                                                    unsigned short* __restrict__ Wt2,
                                                    unsigned short* __restrict__ Wt3) {
    int i = blockIdx.x * 256 + threadIdx.x;
    if (i < 16384) {
        int n = i >> 8, k = i & 255;
        Wtf[i] = f2bf(Wf[k * cFEAT_HID + n]);
        return;
    }
    i -= 16384;
    if (i < 128 * cKPAD) {
        int n = i / cKPAD, k = i - n * cKPAD;
        Wt1[i] = (k < cIN_CH) ? f2bf(W1[k * cHID + n]) : 0;
        return;
    }
    i -= 128 * cKPAD;
    if (i < 128 * 128) {
        int n = i >> 7, k = i & 127;
        Wt2[i] = f2bf(W2[k * cHID + n]);
        return;
    }
    i -= 128 * 128;
    if (i < 48 * 128) {
        int n = i >> 7, k = i & 127;
        Wt3[i] = (n < cNUM_CLASSES) ? f2bf(W3[k * cNUM_CLASSES + n]) : 0;
    }
}

// ---------------- xb[:, 0:40] = bf16(logits) ----------------
__global__ void copy_logits_kernel(const float* __restrict__ logits, unsigned short* __restrict__ xb) {
    int idx = blockIdx.x * blockDim.x + threadIdx.x;
    if (idx < cN * cNUM_CLASSES) {
        int i = idx / cNUM_CLASSES;
        int c = idx - i * cNUM_CLASSES;
        xb[(size_t)i * cKPAD + c] = f2bf(logits[idx]);
    }
}

// ---------------- xb[:, 104:136] = bf16(deg_table[clip(deg)]) ; xb[:, 136:160] = 0 ----------------
__global__ void degemb_kernel(const int* __restrict__ count_src, const int* __restrict__ count_dst,
                              const float* __restrict__ deg_table, unsigned short* __restrict__ xb) {
    constexpr int W = cDEG_HID + 24; // 56 columns: 104..159
    int idx = blockIdx.x * blockDim.x + threadIdx.x;
    if (idx < cN * W) {
        int i = idx / W;
        int j = idx - i * W;
        unsigned short v = 0;
        if (j < cDEG_HID) {
            int deg = count_src[i] + count_dst[i];
            if (deg > cMAX_DEG - 1) deg = cMAX_DEG - 1;
            v = f2bf(deg_table[deg * cDEG_HID + j]);
        }
        xb[(size_t)i * cKPAD + cNUM_CLASSES + cFEAT_HID + j] = v;
    }
}

// ---------------- MFMA GEMM: out[m][n] = A[m][:K] @ Bt[n][:K]^T (+bias), bf16 out ----------------
// Block: 64 rows x NT*16 cols, 256 threads (4 waves). Wave w owns rows w*16..w*16+15, all NT col-tiles.
template <int ASTR, int KTOT, int NT, int OSTR, int OOFF, int OUTC, bool AFP32, bool BIAS>
__global__ __launch_bounds__(256) void mfma_gemm(const void* __restrict__ Av,
                                                 const unsigned short* __restrict__ Bt,
                                                 const float* __restrict__ bias,
                                                 unsigned short* __restrict__ out) {
    __shared__ unsigned short As[64 * 32];      // As[m][k] stride 32
    __shared__ unsigned short Bs[NT * 16 * 32]; // Bs[n][k] stride 32

    const int tid = threadIdx.x;
    const int wave = tid >> 6;
    const int lane = tid & 63;
    const int m15 = lane & 15;
    const int q = lane >> 4;
    const int rowbase = blockIdx.x * 64;

    float4_t acc[NT];
    #pragma unroll
    for (int t = 0; t < NT; ++t) acc[t] = (float4_t){0.f, 0.f, 0.f, 0.f};

    const int arow = tid >> 2;            // 0..63
    const int akq = (tid & 3) * 8;        // 0,8,16,24
    int gr = rowbase + arow;
    if (gr > cN - 1) gr = cN - 1;

    for (int k0 = 0; k0 < KTOT; k0 += 32) {
        // stage A (64x32 bf16)
        if constexpr (AFP32) {
            const float* ap = (const float*)Av + (size_t)gr * ASTR + k0 + akq;
            float4 v0 = *(const float4*)ap;
            float4 v1 = *(const float4*)(ap + 4);
            ushort8_t o = { f2bf(v0.x), f2bf(v0.y), f2bf(v0.z), f2bf(v0.w),
                            f2bf(v1.x), f2bf(v1.y), f2bf(v1.z), f2bf(v1.w) };
            *(ushort8_t*)&As[arow * 32 + akq] = o;
        } else {
            const unsigned short* ap = (const unsigned short*)Av + (size_t)gr * ASTR + k0 + akq;
            *(ushort8_t*)&As[arow * 32 + akq] = *(const ushort8_t*)ap;
        }
        // stage B (NT*16 x 32 bf16) from Bt[n][k]
        for (int i = tid; i < NT * 64; i += 256) {
            int n = i >> 2;
            int kq = (i & 3) * 8;
            *(ushort8_t*)&Bs[n * 32 + kq] = *(const ushort8_t*)&Bt[(size_t)n * KTOT + k0 + kq];
        }
        __syncthreads();

        short8_t a = *(const short8_t*)&As[(wave * 16 + m15) * 32 + q * 8];
        #pragma unroll
        for (int t = 0; t < NT; ++t) {
            short8_t b = *(const short8_t*)&Bs[(t * 16 + m15) * 32 + q * 8];
            acc[t] = __builtin_amdgcn_mfma_f32_16x16x32_bf16(a, b, acc[t], 0, 0, 0);
        }
        __syncthreads();
    }

    // epilogue: D[row=q*4+r][col=m15] per tile
    #pragma unroll
    for (int t = 0; t < NT; ++t) {
        int col = t * 16 + m15;
        if (OUTC % 16 != 0 && col >= OUTC) continue;
        float bv = BIAS ? bias[col] : 0.f;
        #pragma unroll
        for (int r = 0; r < 4; ++r) {
            int row = rowbase + wave * 16 + q * 4 + r;
            if (row < cN)
                out[(size_t)row * OSTR + OOFF + col] = f2bf(acc[t][r] + bv);
        }
    }
}

// ---------------- GCN aggregate over bf16 t, 128 channels -> bf16 out ----------------
template <bool RELU>
__global__ __launch_bounds__(256) void agg_bf128(const unsigned short* __restrict__ t,
                                                 const int* __restrict__ rowptr,
                                                 const int* __restrict__ adj,
                                                 const float* __restrict__ dinv,
                                                 const float* __restrict__ b,
                                                 unsigned short* __restrict__ outb) {
    const int tid = threadIdx.x;
    const int lane = tid & 15;
    const int row = blockIdx.x * 16 + (tid >> 4);
    if (row >= cN) return;
    const int c = lane * 8;
    const float di = dinv[row];
    const int beg = rowptr[row], end = rowptr[row + 1];
    float acc[8];
    #pragma unroll
    for (int k = 0; k < 8; ++k) acc[k] = 0.f;
    for (int e = beg; e < end; ++e) {
        int j = adj[e];
        float vj = dinv[j];
        ushort8_t tv = *(const ushort8_t*)&t[(size_t)j * cHID + c];
        #pragma unroll
        for (int k = 0; k < 8; ++k) acc[k] += vj * bf2f(tv[k]);
    }
    ushort8_t ts = *(const ushort8_t*)&t[(size_t)row * cHID + c];
    const float d2 = di * di;
    ushort8_t o;
    #pragma unroll
    for (int k = 0; k < 8; ++k) {
        float r = di * acc[k] + d2 * bf2f(ts[k]) + b[c + k];
        if (RELU) r = fmaxf(r, 0.f);
        o[k] = f2bf(r);
    }
    *(ushort8_t*)&outb[(size_t)row * cHID + c] = o;
}

// ---------------- GCN aggregate over bf16 t, 40 channels (final, fp32 out) ----------------
__global__ __launch_bounds__(256) void agg_bf40(const unsigned short* __restrict__ t,
                                                const int* __restrict__ rowptr,
                                                const int* __restrict__ adj,
                                                const float* __restrict__ dinv,
                                                const float* __restrict__ b,
                                                float* __restrict__ out) {
    const int tid = threadIdx.x;
    const int lane = tid & 7;
    const int row = blockIdx.x * 32 + (tid >> 3);
    if (row >= cN) return;
    const int c = lane * 8;
    if (c >= cNUM_CLASSES) return;
    const float di = dinv[row];
    const int beg = rowptr[row], end = rowptr[row + 1];
    float acc[8];
    #pragma unroll
    for (int k = 0; k < 8; ++k) acc[k] = 0.f;
    for (int e = beg; e < end; ++e) {
        int j = adj[e];
        float vj = dinv[j];
        ushort8_t tv = *(const ushort8_t*)&t[(size_t)j * cNUM_CLASSES + c];
        #pragma unroll
        for (int k = 0; k < 8; ++k) acc[k] += vj * bf2f(tv[k]);
    }
    ushort8_t ts = *(const ushort8_t*)&t[(size_t)row * cNUM_CLASSES + c];
    const float d2 = di * di;
    float r[8];
    #pragma unroll
    for (int k = 0; k < 8; ++k) r[k] = di * acc[k] + d2 * bf2f(ts[k]) + b[c + k];
    float4 v0 = make_float4(r[0], r[1], r[2], r[3]);
    float4 v1 = make_float4(r[4], r[5], r[6], r[7]);
    *(float4*)&out[(size_t)row * cNUM_CLASSES + c] = v0;
    *(float4*)&out[(size_t)row * cNUM_CLASSES + c + 4] = v1;
}

extern "C" void kernel_launch(void* const* d_in, const int* in_sizes, int n_in,
                              void* d_out, int out_size, void* d_ws, size_t ws_size,
                              hipStream_t stream) {
    const float* logits    = (const float*)d_in[0];
    const float* features  = (const float*)d_in[1];
    const int*   edge      = (const int*)d_in[2];
    const float* Wf        = (const float*)d_in[3];
    const float* bf        = (const float*)d_in[4];
    const float* deg_table = (const float*)d_in[5];
    const float* W1        = (const float*)d_in[6];
    const float* b1        = (const float*)d_in[7];
    const float* W2        = (const float*)d_in[8];
    const float* b2        = (const float*)d_in[9];
    const float* W3        = (const float*)d_in[10];
    const float* b3        = (const float*)d_in[11];
    float* out = (float*)d_out;

    // workspace carve-up (16B-aligned sections)
    int* count_src = (int*)d_ws;                 // N
    int* count_dst = count_src + cN;             // N
    int* rowptr    = count_dst + cN;             // N+1 (padded)
    int* adj       = rowptr + cN + 16;           // E
    int* bsum      = adj + cE;                   // 256
    int* boff      = bsum + 256;                 // 256
    float* dinv    = (float*)(boff + 256);       // N
    unsigned short* xb  = (unsigned short*)(dinv + cN);            // N*160 bf16
    unsigned short* tb  = xb + (size_t)cN * cKPAD;                 // N*128 bf16
    unsigned short* hb  = tb + (size_t)cN * cHID;                  // N*128 bf16
    unsigned short* Wtf = hb + (size_t)cN * cHID;                  // 64*256
    unsigned short* Wt1 = Wtf + 64 * 256;                          // 128*160
    unsigned short* Wt2 = Wt1 + 128 * cKPAD;                       // 128*128
    unsigned short* Wt3 = Wt2 + 128 * 128;                         // 48*128
    unsigned* partial = (unsigned*)(Wt3 + 48 * 128);               // 2*128*25000 u32

    // weights -> bf16 transposed (independent of graph build)
    constexpr int WTOT = 16384 + 128 * cKPAD + 128 * 128 + 48 * 128;
    wconv_kernel<<<(WTOT + 255) / 256, 256, 0, stream>>>(Wf, W1, W2, W3, Wtf, Wt1, Wt2, Wt3);

    // CSR + degrees, no global atomics
    hist_kernel<<<512, 256, 0, stream>>>(edge, partial);
    merge_scan_kernel<<<(cWORDS + 255) / 256, 256, 0, stream>>>(partial, count_src, count_dst);
    block_sum_kernel<<<cSCAN_NB, 256, 0, stream>>>(count_dst, bsum);
    scan_sums_kernel<<<1, 256, 0, stream>>>(bsum, boff);
    write_rowptr_kernel<<<cSCAN_NB, 256, 0, stream>>>(count_dst, boff, rowptr, dinv);
    scatter2_kernel<<<256, 256, 0, stream>>>(edge, partial, rowptr, adj);

    // frontend -> xb (bf16, N x 160, cols 136..159 zero)
    copy_logits_kernel<<<(cN * cNUM_CLASSES + 255) / 256, 256, 0, stream>>>(logits, xb);
    degemb_kernel<<<(cN * (cDEG_HID + 24) + 255) / 256, 256, 0, stream>>>(count_src, count_dst, deg_table, xb);

    constexpr int MB = (cN + 63) / 64; // 782

    // featlin: xb[:,40:104] = bf16(features @ Wf + bf)   (fp32 A, K=256, NT=4)
    mfma_gemm<cFEAT_DIM, 256, 4, cKPAD, cNUM_CLASSES, 64, true, true>
        <<<MB, 256, 0, stream>>>(features, Wtf, bf, xb);

    // conv1: tb = bf16(xb @ W1) ; hb = bf16(relu(agg(tb) + b1))
    mfma_gemm<cKPAD, cKPAD, 8, cHID, 0, cHID, false, false>
        <<<MB, 256, 0, stream>>>(xb, Wt1, nullptr, tb);
    agg_bf128<true><<<(cN + 15) / 16, 256, 0, stream>>>(tb, rowptr, adj, dinv, b1, hb);

    // conv2: tb = bf16(hb @ W2) ; hb = bf16(relu(agg(tb) + b2))
    mfma_gemm<cHID, cHID, 8, cHID, 0, cHID, false, false>
        <<<MB, 256, 0, stream>>>(hb, Wt2, nullptr, tb);
    agg_bf128<true><<<(cN + 15) / 16, 256, 0, stream>>>(tb, rowptr, adj, dinv, b2, hb);

    // conv3: tb = bf16(hb @ W3) ; out = agg(tb) + b3  (fp32 out)
    mfma_gemm<cHID, cHID, 3, cNUM_CLASSES, 0, cNUM_CLASSES, false, false>
        <<<MB, 256, 0, stream>>>(hb, Wt3, nullptr, tb);
    agg_bf40<<<(cN + 31) / 32, 256, 0, stream>>>(tb, rowptr, adj, dinv, b3, out);
}

// Round 8
// 322.932 us; speedup vs baseline: 1.5519x; 1.0607x over previous
//
#include <hip/hip_runtime.h>
#include <hip/hip_bf16.h>

// Problem constants (match reference)
constexpr int cN = 50000;
constexpr int cE = 800000;
constexpr int cNUM_CLASSES = 40;
constexpr int cFEAT_DIM = 256;
constexpr int cFEAT_HID = 64;
constexpr int cDEG_HID = 32;
constexpr int cHID = 128;
constexpr int cIN_CH = cNUM_CLASSES + cFEAT_HID + cDEG_HID; // 136
constexpr int cKPAD = 160;              // IN_CH padded to multiple of 32
constexpr int cMAX_DEG = 256;

// LDS-histogram CSR build parameters
constexpr int cNCHUNK = 128;            // edge chunks (= copies per histogram)
constexpr int cCHUNK  = cE / cNCHUNK;   // 6250 edges per chunk (exact)
constexpr int cWORDS  = cN / 2;         // 25000 packed u16-pair words per histogram
constexpr int cHWORDS = cWORDS / 2;     // 12500 words per node-range half (50 KB LDS)
constexpr int cSCANB  = (cWORDS + 255) / 256; // 98 blocks for mega_scan

typedef unsigned short ushort8_t __attribute__((ext_vector_type(8)));
typedef short short8_t __attribute__((ext_vector_type(8)));
typedef float float4_t __attribute__((ext_vector_type(4)));

__device__ __forceinline__ unsigned short f2bf(float f) {
    unsigned u = __builtin_bit_cast(unsigned, f);
    u += 0x7fff + ((u >> 16) & 1); // RNE
    return (unsigned short)(u >> 16);
}
__device__ __forceinline__ float bf2f(unsigned short s) {
    unsigned u = ((unsigned)s) << 16;
    return __builtin_bit_cast(float, u);
}

// ---------------- prep: LDS histograms (blocks 0..511) + weight convert (blocks 512+) ----------------
// hist: partial[which][chunk][word] (packed u16 pair); cb=b&127, half=(b>>7)&1, which=b>>8
__global__ __launch_bounds__(256) void prep_kernel(const int* __restrict__ edge,
                                                   unsigned* __restrict__ partial,
                                                   const float* __restrict__ Wf,
                                                   const float* __restrict__ W1,
                                                   const float* __restrict__ W2,
                                                   const float* __restrict__ W3,
                                                   unsigned short* __restrict__ Wtf,
                                                   unsigned short* __restrict__ Wt1,
                                                   unsigned short* __restrict__ Wt2,
                                                   unsigned short* __restrict__ Wt3) {
    __shared__ unsigned lds[cHWORDS];
    const int b = blockIdx.x, tid = threadIdx.x;
    if (b < 512) {
        const int cb = b & (cNCHUNK - 1);
        const int half = (b >> 7) & 1;
        const int which = b >> 8;
        for (int i = tid; i < cHWORDS; i += 256) lds[i] = 0;
        __syncthreads();
        const int* ids = edge + (size_t)which * cE + (size_t)cb * cCHUNK;
        const int lo = half * (cN / 2), hi = lo + cN / 2;
        const int wbase = half * cHWORDS;
        for (int i = tid; i < cCHUNK; i += 256) {
            int v = ids[i];
            if (v >= lo && v < hi)
                atomicAdd(&lds[(v >> 1) - wbase], 1u << ((v & 1) * 16));
        }
        __syncthreads();
        unsigned* outp = partial + ((size_t)which * cNCHUNK + cb) * cWORDS + wbase;
        for (int i = tid; i < cHWORDS; i += 256) outp[i] = lds[i];
        return;
    }
    // weight convert+transpose
    int i = (b - 512) * 256 + tid;
    if (i < 16384) {
        int n = i >> 8, k = i & 255;
        Wtf[i] = f2bf(Wf[k * cFEAT_HID + n]);
        return;
    }
    i -= 16384;
    if (i < 128 * cKPAD) {
        int n = i / cKPAD, k = i - n * cKPAD;
        Wt1[i] = (k < cIN_CH) ? f2bf(W1[k * cHID + n]) : 0;
        return;
    }
    i -= 128 * cKPAD;
    if (i < 128 * 128) {
        int n = i >> 7, k = i & 127;
        Wt2[i] = f2bf(W2[k * cHID + n]);
        return;
    }
    i -= 128 * 128;
    if (i < 48 * 128) {
        int n = i >> 7, k = i & 127;
        Wt3[i] = (n < cNUM_CLASSES) ? f2bf(W3[k * cNUM_CLASSES + n]) : 0;
    }
}

// ---------------- mega_scan: merge copies, chunk-prefix rewrite, counts, rowptr, dinv ----------------
// One launch replaces merge_scan + block_sum + scan_sums + write_rowptr via parallel lookback.
// grid = 98 blocks (all co-resident; block b waits only on lower-indexed blocks).
__global__ __launch_bounds__(256) void mega_scan_kernel(unsigned* __restrict__ partial,
                                                        int* __restrict__ count_src,
                                                        int* __restrict__ count_dst,
                                                        int* __restrict__ rowptr,
                                                        float* __restrict__ dinv,
                                                        int* __restrict__ desc) {
    const int b = blockIdx.x, tid = threadIdx.x;
    const int w = b * 256 + tid;
    unsigned slo = 0, shi = 0, plo = 0, phi = 0;
    if (w < cWORDS) {
        const unsigned* ps = partial + w;
        for (int c = 0; c < cNCHUNK; ++c) {
            unsigned v = ps[(size_t)c * cWORDS];
            slo += v & 0xFFFFu; shi += v >> 16;
        }
        *(int2*)&count_src[2 * w] = make_int2((int)slo, (int)shi);
        unsigned* pd = partial + (size_t)cNCHUNK * cWORDS + w;
        for (int c = 0; c < cNCHUNK; ++c) {
            unsigned v = pd[(size_t)c * cWORDS];
            pd[(size_t)c * cWORDS] = plo | (phi << 16);   // per-chunk prefix (fits u16)
            plo += v & 0xFFFFu; phi += v >> 16;
        }
        *(int2*)&count_dst[2 * w] = make_int2((int)plo, (int)phi);
    }
    // local exclusive scan of per-thread totals
    __shared__ int s[256];
    __shared__ int pre[cSCANB];
    int tot = (int)(plo + phi);
    s[tid] = tot;
    __syncthreads();
    #pragma unroll
    for (int off = 1; off < 256; off <<= 1) {
        int t = (tid >= off) ? s[tid - off] : 0;
        __syncthreads();
        s[tid] += t;
        __syncthreads();
    }
    int ex_local = s[tid] - tot;
    int block_total = s[255];
    // publish aggregate, then wait (in parallel) for all predecessors
    if (tid == 0) atomicExch(&desc[b], block_total + 1);
    if (tid < b) {
        int v;
        do { v = atomicAdd(&desc[tid], 0); } while (v == 0);
        s[tid] = v - 1;
    }
    __syncthreads();
    // reduce predecessor sum: tree over s[0..b-1] (pad with zeros)
    if (tid >= b) s[tid] = 0;
    __syncthreads();
    #pragma unroll
    for (int off = 128; off > 0; off >>= 1) {
        if (tid < off) s[tid] += s[tid + off];
        __syncthreads();
    }
    int base = s[0] + ex_local;
    if (w < cWORDS) {
        rowptr[2 * w]     = base;
        rowptr[2 * w + 1] = base + (int)plo;
        dinv[2 * w]     = rsqrtf((float)(plo + 1));
        dinv[2 * w + 1] = rsqrtf((float)(phi + 1));
    }
    if (b == 0 && tid == 0) rowptr[cN] = cE;
    (void)pre;
}

// ---------------- deterministic scatter (no global atomics) ----------------
__global__ __launch_bounds__(256) void scatter2_kernel(const int* __restrict__ edge,
                                                       const unsigned* __restrict__ partial,
                                                       const int* __restrict__ rowptr,
                                                       int* __restrict__ adj) {
    __shared__ unsigned lds[cHWORDS];
    const int b = blockIdx.x, tid = threadIdx.x;
    const int cb = b & (cNCHUNK - 1);
    const int half = b >> 7;
    const int wbase = half * cHWORDS;
    const unsigned* pp = partial + ((size_t)cNCHUNK + cb) * cWORDS + wbase;
    for (int i = tid; i < cHWORDS; i += 256) lds[i] = pp[i];
    __syncthreads();
    const int* srcs = edge + (size_t)cb * cCHUNK;
    const int* dsts = edge + cE + (size_t)cb * cCHUNK;
    const int lo = half * (cN / 2), hi = lo + cN / 2;
    for (int i = tid; i < cCHUNK; i += 256) {
        int d = dsts[i];
        if (d >= lo && d < hi) {
            int sh = (d & 1) * 16;
            unsigned old = atomicAdd(&lds[(d >> 1) - wbase], 1u << sh);
            int off = (int)((old >> sh) & 0xFFFFu);
            adj[rowptr[d] + off] = srcs[i];
        }
    }
}

// ---------------- frontend: xb[:,0:40]=bf16(logits); xb[:,104:136]=deg_emb; xb[:,136:160]=0 ----------------
__global__ __launch_bounds__(256) void frontend_kernel(const float* __restrict__ logits,
                                                       const int* __restrict__ count_src,
                                                       const int* __restrict__ count_dst,
                                                       const float* __restrict__ deg_table,
                                                       unsigned short* __restrict__ xb) {
    constexpr int W = cNUM_CLASSES + cDEG_HID + 24; // 96 columns handled per row
    int idx = blockIdx.x * 256 + threadIdx.x;
    if (idx >= cN * W) return;
    int i = idx / W;
    int j = idx - i * W;
    if (j < cNUM_CLASSES) {
        xb[(size_t)i * cKPAD + j] = f2bf(logits[(size_t)i * cNUM_CLASSES + j]);
    } else {
        int jj = j - cNUM_CLASSES; // 0..55 -> cols 104..159
        unsigned short v = 0;
        if (jj < cDEG_HID) {
            int deg = count_src[i] + count_dst[i];
            if (deg > cMAX_DEG - 1) deg = cMAX_DEG - 1;
            v = f2bf(deg_table[deg * cDEG_HID + jj]);
        }
        xb[(size_t)i * cKPAD + cNUM_CLASSES + cFEAT_HID + jj] = v;
    }
}

// ---------------- MFMA GEMM: out[m][n] = A[m][:K] @ Bt[n][:K]^T (+bias), bf16 out ----------------
template <int ASTR, int KTOT, int NT, int OSTR, int OOFF, int OUTC, bool AFP32, bool BIAS>
__global__ __launch_bounds__(256) void mfma_gemm(const void* __restrict__ Av,
                                                 const unsigned short* __restrict__ Bt,
                                                 const float* __restrict__ bias,
                                                 unsigned short* __restrict__ out) {
    __shared__ unsigned short As[64 * 32];      // As[m][k] stride 32
    __shared__ unsigned short Bs[NT * 16 * 32]; // Bs[n][k] stride 32

    const int tid = threadIdx.x;
    const int wave = tid >> 6;
    const int lane = tid & 63;
    const int m15 = lane & 15;
    const int q = lane >> 4;
    const int rowbase = blockIdx.x * 64;

    float4_t acc[NT];
    #pragma unroll
    for (int t = 0; t < NT; ++t) acc[t] = (float4_t){0.f, 0.f, 0.f, 0.f};

    const int arow = tid >> 2;            // 0..63
    const int akq = (tid & 3) * 8;        // 0,8,16,24
    int gr = rowbase + arow;
    if (gr > cN - 1) gr = cN - 1;

    for (int k0 = 0; k0 < KTOT; k0 += 32) {
        if constexpr (AFP32) {
            const float* ap = (const float*)Av + (size_t)gr * ASTR + k0 + akq;
            float4 v0 = *(const float4*)ap;
            float4 v1 = *(const float4*)(ap + 4);
            ushort8_t o = { f2bf(v0.x), f2bf(v0.y), f2bf(v0.z), f2bf(v0.w),
                            f2bf(v1.x), f2bf(v1.y), f2bf(v1.z), f2bf(v1.w) };
            *(ushort8_t*)&As[arow * 32 + akq] = o;
        } else {
            const unsigned short* ap = (const unsigned short*)Av + (size_t)gr * ASTR + k0 + akq;
            *(ushort8_t*)&As[arow * 32 + akq] = *(const ushort8_t*)ap;
        }
        for (int i = tid; i < NT * 64; i += 256) {
            int n = i >> 2;
            int kq = (i & 3) * 8;
            *(ushort8_t*)&Bs[n * 32 + kq] = *(const ushort8_t*)&Bt[(size_t)n * KTOT + k0 + kq];
        }
        __syncthreads();

        short8_t a = *(const short8_t*)&As[(wave * 16 + m15) * 32 + q * 8];
        #pragma unroll
        for (int t = 0; t < NT; ++t) {
            short8_t b = *(const short8_t*)&Bs[(t * 16 + m15) * 32 + q * 8];
            acc[t] = __builtin_amdgcn_mfma_f32_16x16x32_bf16(a, b, acc[t], 0, 0, 0);
        }
        __syncthreads();
    }

    #pragma unroll
    for (int t = 0; t < NT; ++t) {
        int col = t * 16 + m15;
        if (OUTC % 16 != 0 && col >= OUTC) continue;
        float bv = BIAS ? bias[col] : 0.f;
        #pragma unroll
        for (int r = 0; r < 4; ++r) {
            int row = rowbase + wave * 16 + q * 4 + r;
            if (row < cN)
                out[(size_t)row * OSTR + OOFF + col] = f2bf(acc[t][r] + bv);
        }
    }
}

// ---------------- GCN aggregate over bf16 t, 128 channels -> bf16 out (2-edge unrolled) ----------------
template <bool RELU>
__global__ __launch_bounds__(128) void agg_bf128(const unsigned short* __restrict__ t,
                                                 const int* __restrict__ rowptr,
                                                 const int* __restrict__ adj,
                                                 const float* __restrict__ dinv,
                                                 const float* __restrict__ b,
                                                 unsigned short* __restrict__ outb) {
    const int tid = threadIdx.x;
    const int lane = tid & 15;
    const int row = blockIdx.x * 8 + (tid >> 4);
    if (row >= cN) return;
    const int c = lane * 8;
    const float di = dinv[row];
    int e = rowptr[row];
    const int end = rowptr[row + 1];
    float a0[8], a1[8];
    #pragma unroll
    for (int k = 0; k < 8; ++k) { a0[k] = 0.f; a1[k] = 0.f; }
    for (; e + 1 < end; e += 2) {
        int j0 = adj[e], j1 = adj[e + 1];
        float v0 = dinv[j0], v1 = dinv[j1];
        ushort8_t t0 = *(const ushort8_t*)&t[(size_t)j0 * cHID + c];
        ushort8_t t1 = *(const ushort8_t*)&t[(size_t)j1 * cHID + c];
        #pragma unroll
        for (int k = 0; k < 8; ++k) {
            a0[k] += v0 * bf2f(t0[k]);
            a1[k] += v1 * bf2f(t1[k]);
        }
    }
    if (e < end) {
        int j0 = adj[e];
        float v0 = dinv[j0];
        ushort8_t t0 = *(const ushort8_t*)&t[(size_t)j0 * cHID + c];
        #pragma unroll
        for (int k = 0; k < 8; ++k) a0[k] += v0 * bf2f(t0[k]);
    }
    ushort8_t ts = *(const ushort8_t*)&t[(size_t)row * cHID + c];
    const float d2 = di * di;
    ushort8_t o;
    #pragma unroll
    for (int k = 0; k < 8; ++k) {
        float r = di * (a0[k] + a1[k]) + d2 * bf2f(ts[k]) + b[c + k];
        if (RELU) r = fmaxf(r, 0.f);
        o[k] = f2bf(r);
    }
    *(ushort8_t*)&outb[(size_t)row * cHID + c] = o;
}

// ---------------- GCN aggregate over bf16 t, 40 channels (final, fp32 out, 2-edge unrolled) ----------------
__global__ __launch_bounds__(128) void agg_bf40(const unsigned short* __restrict__ t,
                                                const int* __restrict__ rowptr,
                                                const int* __restrict__ adj,
                                                const float* __restrict__ dinv,
                                                const float* __restrict__ b,
                                                float* __restrict__ out) {
    const int tid = threadIdx.x;
    const int lane = tid & 7;
    const int row = blockIdx.x * 16 + (tid >> 3);
    if (row >= cN) return;
    const int c = lane * 8;
    if (c >= cNUM_CLASSES) return;
    const float di = dinv[row];
    int e = rowptr[row];
    const int end = rowptr[row + 1];
    float a0[8], a1[8];
    #pragma unroll
    for (int k = 0; k < 8; ++k) { a0[k] = 0.f; a1[k] = 0.f; }
    for (; e + 1 < end; e += 2) {
        int j0 = adj[e], j1 = adj[e + 1];
        float v0 = dinv[j0], v1 = dinv[j1];
        ushort8_t t0 = *(const ushort8_t*)&t[(size_t)j0 * cNUM_CLASSES + c];
        ushort8_t t1 = *(const ushort8_t*)&t[(size_t)j1 * cNUM_CLASSES + c];
        #pragma unroll
        for (int k = 0; k < 8; ++k) {
            a0[k] += v0 * bf2f(t0[k]);
            a1[k] += v1 * bf2f(t1[k]);
        }
    }
    if (e < end) {
        int j0 = adj[e];
        float v0 = dinv[j0];
        ushort8_t t0 = *(const ushort8_t*)&t[(size_t)j0 * cNUM_CLASSES + c];
        #pragma unroll
        for (int k = 0; k < 8; ++k) a0[k] += v0 * bf2f(t0[k]);
    }
    ushort8_t ts = *(const ushort8_t*)&t[(size_t)row * cNUM_CLASSES + c];
    const float d2 = di * di;
    float r[8];
    #pragma unroll
    for (int k = 0; k < 8; ++k) r[k] = di * (a0[k] + a1[k]) + d2 * bf2f(ts[k]) + b[c + k];
    float4 v0 = make_float4(r[0], r[1], r[2], r[3]);
    float4 v1 = make_float4(r[4], r[5], r[6], r[7]);
    *(float4*)&out[(size_t)row * cNUM_CLASSES + c] = v0;
    *(float4*)&out[(size_t)row * cNUM_CLASSES + c + 4] = v1;
}

extern "C" void kernel_launch(void* const* d_in, const int* in_sizes, int n_in,
                              void* d_out, int out_size, void* d_ws, size_t ws_size,
                              hipStream_t stream) {
    const float* logits    = (const float*)d_in[0];
    const float* features  = (const float*)d_in[1];
    const int*   edge      = (const int*)d_in[2];
    const float* Wf        = (const float*)d_in[3];
    const float* bf        = (const float*)d_in[4];
    const float* deg_table = (const float*)d_in[5];
    const float* W1        = (const float*)d_in[6];
    const float* b1        = (const float*)d_in[7];
    const float* W2        = (const float*)d_in[8];
    const float* b2        = (const float*)d_in[9];
    const float* W3        = (const float*)d_in[10];
    const float* b3        = (const float*)d_in[11];
    float* out = (float*)d_out;

    // workspace carve-up (16B-aligned sections)
    int* count_src = (int*)d_ws;                 // N
    int* count_dst = count_src + cN;             // N
    int* rowptr    = count_dst + cN;             // N+1 (padded)
    int* adj       = rowptr + cN + 16;           // E
    int* desc      = adj + cE;                   // 128
    float* dinv    = (float*)(desc + 128);       // N
    unsigned short* xb  = (unsigned short*)(dinv + cN);            // N*160 bf16
    unsigned short* tb  = xb + (size_t)cN * cKPAD;                 // N*128 bf16
    unsigned short* hb  = tb + (size_t)cN * cHID;                  // N*128 bf16
    unsigned short* Wtf = hb + (size_t)cN * cHID;                  // 64*256
    unsigned short* Wt1 = Wtf + 64 * 256;                          // 128*160
    unsigned short* Wt2 = Wt1 + 128 * cKPAD;                       // 128*128
    unsigned short* Wt3 = Wt2 + 128 * 128;                         // 48*128
    unsigned* partial = (unsigned*)(Wt3 + 48 * 128);               // 2*128*25000 u32

    hipMemsetAsync(desc, 0, 128 * sizeof(int), stream);

    // histograms + weight conversion (one launch)
    constexpr int WTOT = 16384 + 128 * cKPAD + 128 * 128 + 48 * 128;
    constexpr int WBLK = (WTOT + 255) / 256;
    prep_kernel<<<512 + WBLK, 256, 0, stream>>>(edge, partial, Wf, W1, W2, W3, Wtf, Wt1, Wt2, Wt3);

    // merged scan: counts, chunk-prefix rewrite, rowptr, dinv (one launch, parallel lookback)
    mega_scan_kernel<<<cSCANB, 256, 0, stream>>>(partial, count_src, count_dst, rowptr, dinv, desc);

    // CSR scatter (no global atomics)
    scatter2_kernel<<<256, 256, 0, stream>>>(edge, partial, rowptr, adj);

    // frontend -> xb (logits + degree embedding + zero pad)
    frontend_kernel<<<(cN * 96 + 255) / 256, 256, 0, stream>>>(logits, count_src, count_dst, deg_table, xb);

    constexpr int MB = (cN + 63) / 64; // 782

    // featlin: xb[:,40:104] = bf16(features @ Wf + bf)
    mfma_gemm<cFEAT_DIM, 256, 4, cKPAD, cNUM_CLASSES, 64, true, true>
        <<<MB, 256, 0, stream>>>(features, Wtf, bf, xb);

    // conv1
    mfma_gemm<cKPAD, cKPAD, 8, cHID, 0, cHID, false, false>
        <<<MB, 256, 0, stream>>>(xb, Wt1, nullptr, tb);
    agg_bf128<true><<<(cN + 7) / 8, 128, 0, stream>>>(tb, rowptr, adj, dinv, b1, hb);

    // conv2
    mfma_gemm<cHID, cHID, 8, cHID, 0, cHID, false, false>
        <<<MB, 256, 0, stream>>>(hb, Wt2, nullptr, tb);
    agg_bf128<true><<<(cN + 7) / 8, 128, 0, stream>>>(tb, rowptr, adj, dinv, b2, hb);

    // conv3
    mfma_gemm<cHID, cHID, 3, cNUM_CLASSES, 0, cNUM_CLASSES, false, false>
        <<<MB, 256, 0, stream>>>(hb, Wt3, nullptr, tb);
    agg_bf40<<<(cN + 15) / 16, 128, 0, stream>>>(tb, rowptr, adj, dinv, b3, out);
}